// Round 20
// baseline (130.292 us; speedup 1.0000x reference)
//
#include <hip/hip_runtime.h>
#include <hip/hip_bf16.h>

typedef unsigned short u16;
typedef __attribute__((ext_vector_type(8))) short s16x8;
typedef __attribute__((ext_vector_type(4))) short s16x4;
typedef __attribute__((ext_vector_type(4))) float f32x4;
typedef __attribute__((ext_vector_type(8))) unsigned short u16x8;
typedef __attribute__((ext_vector_type(4))) unsigned int u32x4;
typedef __attribute__((ext_vector_type(2))) unsigned int u32x2;

#define AS1(p) (const __attribute__((address_space(1))) void*)(p)
#define AS3(p) (__attribute__((address_space(3))) void*)(p)

__device__ __forceinline__ u16 f2bf(float f) {
  unsigned u = __builtin_bit_cast(unsigned, f);
  u += 0x7fffu + ((u >> 16) & 1u);
  return (u16)(u >> 16);
}

__device__ __forceinline__ unsigned cvtpk(float lo, float hi) {
  unsigned r;
  asm("v_cvt_pk_bf16_f32 %0, %1, %2" : "=v"(r) : "v"(lo), "v"(hi));
  return r;
}

// ------------- prep: transpose+convert 4 weights only (q/k/v convert fused into GEMM) -------------
__global__ __launch_bounds__(256) void prep_w(const float* __restrict__ wq,
                                              const float* __restrict__ wk,
                                              const float* __restrict__ wv,
                                              const float* __restrict__ wo,
                                              u16* __restrict__ Wqt, u16* __restrict__ Wkt,
                                              u16* __restrict__ Wvt, u16* __restrict__ Wot) {
  __shared__ float t[32][33];
  const int b2 = blockIdx.x, tid = threadIdx.x;
  const int wsel = b2 >> 10;
  const float* w = wsel == 0 ? wq : wsel == 1 ? wk : wsel == 2 ? wv : wo;
  u16* wt = wsel == 0 ? Wqt : wsel == 1 ? Wkt : wsel == 2 ? Wvt : Wot;
  const int n0 = (b2 & 31) * 32, k0 = ((b2 >> 5) & 31) * 32;
  const int tx = tid & 31, ty = tid >> 5;
#pragma unroll
  for (int i = 0; i < 4; i++)
    t[ty + 8 * i][tx] = w[(size_t)(k0 + ty + 8 * i) * 1024 + n0 + tx];
  __syncthreads();
#pragma unroll
  for (int i = 0; i < 4; i++)
    wt[(size_t)(n0 + ty + 8 * i) * 1024 + k0 + tx] = f2bf(t[tx][ty + 8 * i]);
}

// ---------------- fused QKV GEMM: fp32-A staging + in-reg cvt, BK=64, XCD-swizzled ----------------
// A = raw fp32 q/k/v staged to LDS as f32 [128][64] with 16B-chunk XOR-16 swizzle
// (round-14 correctness-proven); XCD remap keeps each XCD's 2MB fp32 A-panel L2-resident
// (round-16 proven). mode 0: Q *0.125*log2e  1: K  2: V -> Vt PV-permuted.
__global__ __launch_bounds__(256) void gemm_qkv(const float* __restrict__ Aq,
                                                const float* __restrict__ Ak,
                                                const float* __restrict__ Av,
                                                const u16* __restrict__ Wqt,
                                                const u16* __restrict__ Wkt,
                                                const u16* __restrict__ Wvt,
                                                const float* __restrict__ bq,
                                                const float* __restrict__ bk,
                                                const float* __restrict__ bv,
                                                u16* __restrict__ Qb, u16* __restrict__ Kb,
                                                u16* __restrict__ Vt) {
  const int mode = blockIdx.z;
  const float* A = mode == 0 ? Aq : mode == 1 ? Ak : Av;
  const u16* Bt = mode == 0 ? Wqt : mode == 1 ? Wkt : Wvt;
  const float* bias = mode == 0 ? bq : mode == 1 ? bk : bv;
  u16* outp = mode == 0 ? Qb : mode == 1 ? Kb : Vt;

  __shared__ float AlsF[128 * 64];  // 32 KB
  __shared__ u16 Bls[128 * 64];     // 16 KB
  const int tid = threadIdx.x;
  const int lane = tid & 63;
  const int wid = tid >> 6;
  const int wm = wid >> 1, wn = wid & 1;
  const int sid = blockIdx.x + (blockIdx.y << 3);
  const int xcd = sid & 7, sj = sid >> 3;
  const int m0 = ((xcd << 2) + (sj & 3)) * 128;
  const int n0 = (sj >> 2) * 128;
  const int g = lane >> 4, c = lane & 15;
  const int srl = lane >> 3, sch0 = lane & 7;   // B staging
  const int arl = lane >> 4, ac15 = lane & 15;  // A staging (4 rows x 16 chunks)
  f32x4 acc[4][4] = {};
  for (int kk = 0; kk < 1024; kk += 64) {
    __syncthreads();
#pragma unroll
    for (int jj = 0; jj < 8; jj++) {  // A: fp32, 4 rows per load
      const int rl = wid * 32 + jj * 4 + arl;
      const int scol = kk + ((ac15 ^ (rl & 15)) << 2);
      __builtin_amdgcn_global_load_lds(AS1(A + (size_t)(m0 + rl) * 1024 + scol),
                                       AS3(&AlsF[(wid * 32 + jj * 4) * 64]), 16, 0, 0);
    }
#pragma unroll
    for (int jj = 0; jj < 4; jj++) {  // B: bf16, proven 8-chunk swizzle
      const int rl = wid * 32 + jj * 8 + srl;
      const int col = kk + ((sch0 ^ (rl & 7)) << 3);
      __builtin_amdgcn_global_load_lds(AS1(Bt + (size_t)(n0 + rl) * 1024 + col),
                                       AS3(&Bls[(wid * 32 + jj * 8) * 64]), 16, 0, 0);
    }
    __syncthreads();
#pragma unroll
    for (int half = 0; half < 2; half++) {
      s16x8 af[4], bfr[4];
#pragma unroll
      for (int mi = 0; mi < 4; mi++) {
        const int r = wm * 64 + mi * 16 + c;
        const int j2 = (half * 4 + g) * 2;
        const f32x4 a0 = *(const f32x4*)&AlsF[r * 64 + ((j2 ^ (r & 15)) << 2)];
        const f32x4 a1 = *(const f32x4*)&AlsF[r * 64 + (((j2 + 1) ^ (r & 15)) << 2)];
        u32x4 ww;
        ww[0] = cvtpk(a0[0], a0[1]);
        ww[1] = cvtpk(a0[2], a0[3]);
        ww[2] = cvtpk(a1[0], a1[1]);
        ww[3] = cvtpk(a1[2], a1[3]);
        af[mi] = __builtin_bit_cast(s16x8, ww);
      }
#pragma unroll
      for (int ni = 0; ni < 4; ni++) {
        const int r = wn * 64 + ni * 16 + c;
        bfr[ni] = *(const s16x8*)&Bls[r * 64 + (((half * 4 + g) ^ (r & 7)) << 3)];
      }
      __builtin_amdgcn_s_setprio(1);
#pragma unroll
      for (int mi = 0; mi < 4; mi++)
#pragma unroll
        for (int ni = 0; ni < 4; ni++)
          acc[mi][ni] = __builtin_amdgcn_mfma_f32_16x16x32_bf16(af[mi], bfr[ni],
                                                                acc[mi][ni], 0, 0, 0);
      __builtin_amdgcn_s_setprio(0);
    }
  }
#pragma unroll
  for (int mi = 0; mi < 4; mi++) {
#pragma unroll
    for (int ni = 0; ni < 4; ni++) {
      const int gn = n0 + wn * 64 + ni * 16 + c;
      const float bb = bias[gn];
      const int gmb = m0 + wm * 64 + mi * 16 + (g << 2);
      const int hd = gn >> 6, d = gn & 63;
      if (mode == 2) {
        const int b = gmb >> 11, s0 = gmb & 2047;
        const int tile = s0 >> 6;
        const int jb = gmb & 63;
        const int j5b = jb & 31;
        const int posb = ((jb >> 5) << 5) + (((j5b & 15) >> 2) << 3) + ((j5b >> 4) << 2);
        s16x4 st;
#pragma unroll
        for (int r = 0; r < 4; r++) st[r] = (short)f2bf(acc[mi][ni][r] + bb);
        *(s16x4*)&Vt[(((size_t)b * 16 + hd) * 64 + d) * 2048 + tile * 64 + posb] = st;
      } else {
#pragma unroll
        for (int r = 0; r < 4; r++) {
          const int gm = gmb + r;
          float val = acc[mi][ni][r] + bb;
          const int b = gm >> 11, s = gm & 2047;
          if (mode == 0) val *= 0.18033688f;  // 0.125 * log2(e)
          outp[(((size_t)b * 16 + hd) * 2048 + s) * 64 + d] = f2bf(val);
        }
      }
    }
  }
}

// ---------------- output GEMM: 128x64 tile, BK=64, XCD-swizzled ----------------
__global__ __launch_bounds__(256) void gemm_out(const u16* __restrict__ A,
                                                const u16* __restrict__ Bt,
                                                const float* __restrict__ bias,
                                                float* __restrict__ outp) {
  __shared__ u16 Als[128 * 64];
  __shared__ u16 Bls[64 * 64];
  const int tid = threadIdx.x;
  const int lane = tid & 63;
  const int wid = tid >> 6;
  const int sid = blockIdx.x + (blockIdx.y << 4);
  const int xcd = sid & 7, sj = sid >> 3;
  const int m0 = ((xcd << 2) + (sj & 3)) * 128;
  const int n0 = (sj >> 2) * 64;
  const int g = lane >> 4, c = lane & 15;
  const int srl = lane >> 3, sch0 = lane & 7;
  f32x4 acc[2][4] = {};
  for (int kk = 0; kk < 1024; kk += 64) {
    __syncthreads();
#pragma unroll
    for (int jj = 0; jj < 4; jj++) {
      const int rl = wid * 32 + jj * 8 + srl;
      const int col = kk + ((sch0 ^ (rl & 7)) << 3);
      __builtin_amdgcn_global_load_lds(AS1(A + (size_t)(m0 + rl) * 1024 + col),
                                       AS3(&Als[(wid * 32 + jj * 8) * 64]), 16, 0, 0);
    }
#pragma unroll
    for (int jj = 0; jj < 2; jj++) {
      const int rl = wid * 16 + jj * 8 + srl;
      const int col = kk + ((sch0 ^ (rl & 7)) << 3);
      __builtin_amdgcn_global_load_lds(AS1(Bt + (size_t)(n0 + rl) * 1024 + col),
                                       AS3(&Bls[(wid * 16 + jj * 8) * 64]), 16, 0, 0);
    }
    __syncthreads();
#pragma unroll
    for (int half = 0; half < 2; half++) {
      s16x8 af[2], bfr[4];
#pragma unroll
      for (int mi = 0; mi < 2; mi++) {
        const int r = wid * 32 + mi * 16 + c;
        af[mi] = *(const s16x8*)&Als[r * 64 + (((half * 4 + g) ^ (r & 7)) << 3)];
      }
#pragma unroll
      for (int ni = 0; ni < 4; ni++) {
        const int r = ni * 16 + c;
        bfr[ni] = *(const s16x8*)&Bls[r * 64 + (((half * 4 + g) ^ (r & 7)) << 3)];
      }
      __builtin_amdgcn_s_setprio(1);
#pragma unroll
      for (int mi = 0; mi < 2; mi++)
#pragma unroll
        for (int ni = 0; ni < 4; ni++)
          acc[mi][ni] = __builtin_amdgcn_mfma_f32_16x16x32_bf16(af[mi], bfr[ni],
                                                                acc[mi][ni], 0, 0, 0);
      __builtin_amdgcn_s_setprio(0);
    }
  }
#pragma unroll
  for (int mi = 0; mi < 2; mi++) {
#pragma unroll
    for (int ni = 0; ni < 4; ni++) {
      const int gn = n0 + ni * 16 + c;
      const float bb = bias[gn];
      const int gmb = m0 + wid * 32 + mi * 16 + (g << 2);
#pragma unroll
      for (int r = 0; r < 4; r++)
        outp[(size_t)(gmb + r) * 1024 + gn] = acc[mi][ni][r] + bb;
    }
  }
}

// ---------------- flash attention: counted-vmcnt + reg-only mask fast path ----------------
__global__ __launch_bounds__(128) void attn_fwd(const u16* __restrict__ Qb,
                                                const u16* __restrict__ Kb,
                                                const u16* __restrict__ Vt,
                                                const float* __restrict__ mask,
                                                u16* __restrict__ ctx) {
  __shared__ u16 Kls[2][4096];
  __shared__ u16 Vls[2][4096];
  __shared__ float Mls[2048];
  const int tid = threadIdx.x;
  const int lane = tid & 63, wid = tid >> 6;  // wid 0..1
  const int n = blockIdx.x;
  const int bh = ((n & 7) << 2) | ((n >> 3) & 3);  // 4 bh per XCD
  const int qblk = n >> 5;                          // 0..31
  const int b = bh >> 4, hd = bh & 15;
  const int g = lane >> 4, c = lane & 15;
  const int qbase = qblk * 64 + wid * 32;

  // mask row -> LDS, pre-scaled (masked path) + reg-only all-zero detection
  const float* mp = mask + (size_t)b * 2048;
  int th_any = 0;
#pragma unroll
  for (int i = 0; i < 4; i++) {
    const int idx = (i * 128 + tid) * 4;
    f32x4 m4 = *(const f32x4*)(mp + idx);
    m4 *= -1.44269504e9f;
    *(f32x4*)&Mls[idx] = m4;
  }
#pragma unroll
  for (int i = 0; i < 8; i++) {  // full-row scan per wave -> wave-uniform verdict
    const f32x4 m4 = *(const f32x4*)(mp + lane * 32 + i * 4);
    th_any |= (m4[0] != 0.f) | (m4[1] != 0.f) | (m4[2] != 0.f) | (m4[3] != 0.f);
  }
  const int havemask = (__ballot(th_any) != 0ULL);

  // Q fragments for both 16-q subtiles, hoisted
  s16x8 qf[2][2];
#pragma unroll
  for (int sub = 0; sub < 2; sub++) {
    const u16* Qp = Qb + ((size_t)bh * 2048 + qbase + sub * 16 + c) * 64;
    qf[sub][0] = *(const s16x8*)(Qp + g * 8);
    qf[sub][1] = *(const s16x8*)(Qp + 32 + g * 8);
  }

  const u16* Kbh = Kb + (size_t)bh * 2048 * 64;
  const u16* Vbh = Vt + (size_t)bh * 64 * 2048;

  const int srl = lane >> 3;
  const int sch0 = lane & 7;
  auto STAGE = [&](int kv0, int bufi) {
#pragma unroll
    for (int jj = 0; jj < 4; jj++) {
      const int rl = wid * 32 + jj * 8 + srl;
      const int sch = sch0 ^ (rl & 7);
      __builtin_amdgcn_global_load_lds(AS1(Kbh + (size_t)(kv0 + rl) * 64 + sch * 8),
                                       AS3(&Kls[bufi][wid * 2048 + jj * 512]), 16, 0, 0);
      __builtin_amdgcn_global_load_lds(AS1(Vbh + (size_t)rl * 2048 + kv0 + sch * 8),
                                       AS3(&Vls[bufi][wid * 2048 + jj * 512]), 16, 0, 0);
    }
  };

  f32x4 o[2][4] = {};
  f32x4 ts2[2] = {};

  STAGE(0, 0);
  STAGE(64, 1);
  asm volatile("s_waitcnt lgkmcnt(0)" ::: "memory");

  for (int t = 0; t < 32; t++) {
    const int kv0 = t * 64;
    const int buf = t & 1;
    if (t < 31) {
      asm volatile("s_waitcnt vmcnt(8)" ::: "memory");
    } else {
      asm volatile("s_waitcnt vmcnt(0)" ::: "memory");
    }
    __builtin_amdgcn_sched_barrier(0);
    __builtin_amdgcn_s_barrier();
    __builtin_amdgcn_sched_barrier(0);

    // ---- QK^T ----
    f32x4 sacc[2][4] = {};
#pragma unroll
    for (int kvt = 0; kvt < 4; kvt++) {
      const int row = kvt * 16 + c;
      const int s7 = row & 7;
      const s16x8 kf0 = *(const s16x8*)&Kls[buf][row * 64 + ((g ^ s7) << 3)];
      const s16x8 kf1 = *(const s16x8*)&Kls[buf][row * 64 + (((4 + g) ^ s7) << 3)];
      sacc[0][kvt] = __builtin_amdgcn_mfma_f32_16x16x32_bf16(kf0, qf[0][0], sacc[0][kvt], 0, 0, 0);
      sacc[0][kvt] = __builtin_amdgcn_mfma_f32_16x16x32_bf16(kf1, qf[0][1], sacc[0][kvt], 0, 0, 0);
      sacc[1][kvt] = __builtin_amdgcn_mfma_f32_16x16x32_bf16(kf0, qf[1][0], sacc[1][kvt], 0, 0, 0);
      sacc[1][kvt] = __builtin_amdgcn_mfma_f32_16x16x32_bf16(kf1, qf[1][1], sacc[1][kvt], 0, 0, 0);
    }

    // ---- V fragments -> regs ----
    s16x8 vreg[4][2];
#pragma unroll
    for (int dblk = 0; dblk < 4; dblk++) {
      const int row = dblk * 16 + c;
      const int s7 = row & 7;
      const u16* base = &Vls[buf][row * 64];
      vreg[dblk][0] = *(const s16x8*)(base + ((g ^ s7) << 3));
      vreg[dblk][1] = *(const s16x8*)(base + (((4 + g) ^ s7) << 3));
    }
    asm volatile("s_waitcnt lgkmcnt(0)" ::: "memory");
    __builtin_amdgcn_sched_barrier(0);
    __builtin_amdgcn_s_barrier();
    __builtin_amdgcn_sched_barrier(0);
    if (t < 30) STAGE(kv0 + 128, buf);

    // ---- softmax: reg-only fast path or general masked path ----
    s16x8 pf[2][2];
    if (!havemask) {
#pragma unroll
      for (int qs = 0; qs < 2; qs++) {
        f32x4 p4[4];
#pragma unroll
        for (int kvt = 0; kvt < 4; kvt++) {
#pragma unroll
          for (int jj = 0; jj < 4; jj++)
            p4[kvt][jj] = __builtin_amdgcn_exp2f(sacc[qs][kvt][jj]);
          ts2[qs] += p4[kvt];
        }
#pragma unroll
        for (int sub = 0; sub < 2; sub++) {
          u32x4 ww;
          ww[0] = cvtpk(p4[sub * 2][0], p4[sub * 2][1]);
          ww[1] = cvtpk(p4[sub * 2][2], p4[sub * 2][3]);
          ww[2] = cvtpk(p4[sub * 2 + 1][0], p4[sub * 2 + 1][1]);
          ww[3] = cvtpk(p4[sub * 2 + 1][2], p4[sub * 2 + 1][3]);
          pf[qs][sub] = __builtin_bit_cast(s16x8, ww);
        }
      }
    } else {
#pragma unroll
      for (int qs = 0; qs < 2; qs++) {
        f32x4 p4[4];
#pragma unroll
        for (int kvt = 0; kvt < 4; kvt++) {
          const f32x4 mk = *(const f32x4*)&Mls[kv0 + kvt * 16 + 4 * g];
#pragma unroll
          for (int jj = 0; jj < 4; jj++)
            p4[kvt][jj] = __builtin_amdgcn_exp2f(sacc[qs][kvt][jj] + mk[jj]);
          ts2[qs] += p4[kvt];
        }
#pragma unroll
        for (int sub = 0; sub < 2; sub++) {
          u32x4 ww;
          ww[0] = cvtpk(p4[sub * 2][0], p4[sub * 2][1]);
          ww[1] = cvtpk(p4[sub * 2][2], p4[sub * 2][3]);
          ww[2] = cvtpk(p4[sub * 2 + 1][0], p4[sub * 2 + 1][1]);
          ww[3] = cvtpk(p4[sub * 2 + 1][2], p4[sub * 2 + 1][3]);
          pf[qs][sub] = __builtin_bit_cast(s16x8, ww);
        }
      }
    }

    // ---- PV from registers ----
#pragma unroll
    for (int dblk = 0; dblk < 4; dblk++)
#pragma unroll
      for (int subk = 0; subk < 2; subk++) {
        o[0][dblk] = __builtin_amdgcn_mfma_f32_16x16x32_bf16(vreg[dblk][subk], pf[0][subk], o[0][dblk], 0, 0, 0);
        o[1][dblk] = __builtin_amdgcn_mfma_f32_16x16x32_bf16(vreg[dblk][subk], pf[1][subk], o[1][dblk], 0, 0, 0);
      }
  }

#pragma unroll
  for (int qs = 0; qs < 2; qs++) {
    float ts = (ts2[qs][0] + ts2[qs][1]) + (ts2[qs][2] + ts2[qs][3]);
    ts += __shfl_xor(ts, 16);
    ts += __shfl_xor(ts, 32);
    const float inv = 1.0f / ts;
    u16* cp = ctx + ((size_t)b * 2048 + qbase + qs * 16 + c) * 1024 + hd * 64;
#pragma unroll
    for (int d = 0; d < 4; d++) {
      u32x2 st;
      st[0] = cvtpk(o[qs][d][0] * inv, o[qs][d][1] * inv);
      st[1] = cvtpk(o[qs][d][2] * inv, o[qs][d][3] * inv);
      *(u32x2*)&cp[d * 16 + 4 * g] = st;
    }
  }
}

extern "C" void kernel_launch(void* const* d_in, const int* in_sizes, int n_in,
                              void* d_out, int out_size, void* d_ws, size_t ws_size,
                              hipStream_t stream) {
  (void)in_sizes; (void)n_in; (void)out_size; (void)ws_size;
  const float* q = (const float*)d_in[0];
  const float* k = (const float*)d_in[1];
  const float* v = (const float*)d_in[2];
  const float* mask = (const float*)d_in[3];
  const float* wq = (const float*)d_in[4];
  const float* bq = (const float*)d_in[5];
  const float* wk = (const float*)d_in[6];
  const float* bk = (const float*)d_in[7];
  const float* wv = (const float*)d_in[8];
  const float* bv = (const float*)d_in[9];
  const float* wo = (const float*)d_in[10];
  const float* bo = (const float*)d_in[11];
  float* out = (float*)d_out;
  char* ws = (char*)d_ws;
  const size_t MB = (size_t)1 << 20;
  u16* ctx = (u16*)(ws + 0 * MB);   // 8 MB
  u16* Wqt = (u16*)(ws + 24 * MB);
  u16* Wkt = (u16*)(ws + 26 * MB);
  u16* Wvt = (u16*)(ws + 28 * MB);
  u16* Wot = (u16*)(ws + 30 * MB);
  u16* Qb = (u16*)(ws + 32 * MB);
  u16* Kb = (u16*)(ws + 40 * MB);
  u16* Vt = (u16*)(ws + 48 * MB);

  prep_w<<<4096, 256, 0, stream>>>(wq, wk, wv, wo, Wqt, Wkt, Wvt, Wot);
  gemm_qkv<<<dim3(8, 32, 3), 256, 0, stream>>>(q, k, v, Wqt, Wkt, Wvt, bq, bk, bv,
                                               Qb, Kb, Vt);
  attn_fwd<<<1024, 128, 0, stream>>>(Qb, Kb, Vt, mask, ctx);
  gemm_out<<<dim3(16, 32), 256, 0, stream>>>(ctx, Wot, bo, out);
}

// Round 21
// 126.784 us; speedup vs baseline: 1.0277x; 1.0277x over previous
//
#include <hip/hip_runtime.h>
#include <hip/hip_bf16.h>

typedef unsigned short u16;
typedef __attribute__((ext_vector_type(8))) short s16x8;
typedef __attribute__((ext_vector_type(4))) short s16x4;
typedef __attribute__((ext_vector_type(4))) float f32x4;
typedef __attribute__((ext_vector_type(8))) unsigned short u16x8;
typedef __attribute__((ext_vector_type(4))) unsigned int u32x4;
typedef __attribute__((ext_vector_type(2))) unsigned int u32x2;

#define AS1(p) (const __attribute__((address_space(1))) void*)(p)
#define AS3(p) (__attribute__((address_space(3))) void*)(p)

__device__ __forceinline__ u16 f2bf(float f) {
  unsigned u = __builtin_bit_cast(unsigned, f);
  u += 0x7fffu + ((u >> 16) & 1u);
  return (u16)(u >> 16);
}

__device__ __forceinline__ unsigned cvtpk(float lo, float hi) {
  unsigned r;
  asm("v_cvt_pk_bf16_f32 %0, %1, %2" : "=v"(r) : "v"(lo), "v"(hi));
  return r;
}

// ------------- fused prep: cvt q/k/v -> bf16  +  transpose 4 weights -------------
__global__ __launch_bounds__(256) void prep(const float* __restrict__ q,
                                            const float* __restrict__ k,
                                            const float* __restrict__ v,
                                            const float* __restrict__ wq,
                                            const float* __restrict__ wk,
                                            const float* __restrict__ wv,
                                            const float* __restrict__ wo,
                                            u16* __restrict__ Xq, u16* __restrict__ Xk,
                                            u16* __restrict__ Xv, u16* __restrict__ Wqt,
                                            u16* __restrict__ Wkt, u16* __restrict__ Wvt,
                                            u16* __restrict__ Wot) {
  __shared__ float t[32][33];
  const int bid = blockIdx.x, tid = threadIdx.x;
  if (bid < 6144) {
    const int m = bid >> 11;
    const float* in = m == 0 ? q : m == 1 ? k : v;
    u16* out = m == 0 ? Xq : m == 1 ? Xk : Xv;
    const int i = ((bid & 2047) * 256 + tid) * 8;
    f32x4 a = *(const f32x4*)(in + i);
    f32x4 b = *(const f32x4*)(in + i + 4);
    u16x8 r;
    r[0] = f2bf(a[0]); r[1] = f2bf(a[1]); r[2] = f2bf(a[2]); r[3] = f2bf(a[3]);
    r[4] = f2bf(b[0]); r[5] = f2bf(b[1]); r[6] = f2bf(b[2]); r[7] = f2bf(b[3]);
    *(u16x8*)(out + i) = r;
  } else {
    const int b2 = bid - 6144;
    const int wsel = b2 >> 10;
    const float* w = wsel == 0 ? wq : wsel == 1 ? wk : wsel == 2 ? wv : wo;
    u16* wt = wsel == 0 ? Wqt : wsel == 1 ? Wkt : wsel == 2 ? Wvt : Wot;
    const int n0 = (b2 & 31) * 32, k0 = ((b2 >> 5) & 31) * 32;
    const int tx = tid & 31, ty = tid >> 5;
#pragma unroll
    for (int i = 0; i < 4; i++)
      t[ty + 8 * i][tx] = w[(size_t)(k0 + ty + 8 * i) * 1024 + n0 + tx];
    __syncthreads();
#pragma unroll
    for (int i = 0; i < 4; i++)
      wt[(size_t)(n0 + ty + 8 * i) * 1024 + k0 + tx] = f2bf(t[tx][ty + 8 * i]);
  }
}

// ---------------- fused QKV GEMM, BK=64, XCD-swizzled: mode = blockIdx.z ----------------
__global__ __launch_bounds__(256) void gemm_qkv(const u16* __restrict__ Xq,
                                                const u16* __restrict__ Xk,
                                                const u16* __restrict__ Xv,
                                                const u16* __restrict__ Wqt,
                                                const u16* __restrict__ Wkt,
                                                const u16* __restrict__ Wvt,
                                                const float* __restrict__ bq,
                                                const float* __restrict__ bk,
                                                const float* __restrict__ bv,
                                                u16* __restrict__ Qb, u16* __restrict__ Kb,
                                                u16* __restrict__ Vt) {
  const int mode = blockIdx.z;
  const u16* A = mode == 0 ? Xq : mode == 1 ? Xk : Xv;
  const u16* Bt = mode == 0 ? Wqt : mode == 1 ? Wkt : Wvt;
  const float* bias = mode == 0 ? bq : mode == 1 ? bk : bv;
  u16* outp = mode == 0 ? Qb : mode == 1 ? Kb : Vt;

  __shared__ u16 Als[128 * 64];
  __shared__ u16 Bls[128 * 64];
  const int tid = threadIdx.x;
  const int lane = tid & 63;
  const int wid = tid >> 6;
  const int wm = wid >> 1, wn = wid & 1;
  const int sid = blockIdx.x + (blockIdx.y << 3);
  const int xcd = sid & 7, sj = sid >> 3;
  const int m0 = ((xcd << 2) + (sj & 3)) * 128;
  const int n0 = (sj >> 2) * 128;
  const int g = lane >> 4, c = lane & 15;
  const int srl = lane >> 3, sch0 = lane & 7;
  f32x4 acc[4][4] = {};
  for (int kk = 0; kk < 1024; kk += 64) {
    __syncthreads();
#pragma unroll
    for (int jj = 0; jj < 4; jj++) {
      const int rl = wid * 32 + jj * 8 + srl;
      const int col = kk + ((sch0 ^ (rl & 7)) << 3);
      __builtin_amdgcn_global_load_lds(AS1(A + (size_t)(m0 + rl) * 1024 + col),
                                       AS3(&Als[(wid * 32 + jj * 8) * 64]), 16, 0, 0);
      __builtin_amdgcn_global_load_lds(AS1(Bt + (size_t)(n0 + rl) * 1024 + col),
                                       AS3(&Bls[(wid * 32 + jj * 8) * 64]), 16, 0, 0);
    }
    __syncthreads();
#pragma unroll
    for (int half = 0; half < 2; half++) {
      s16x8 af[4], bfr[4];
#pragma unroll
      for (int mi = 0; mi < 4; mi++) {
        const int r = wm * 64 + mi * 16 + c;
        af[mi] = *(const s16x8*)&Als[r * 64 + (((half * 4 + g) ^ (r & 7)) << 3)];
      }
#pragma unroll
      for (int ni = 0; ni < 4; ni++) {
        const int r = wn * 64 + ni * 16 + c;
        bfr[ni] = *(const s16x8*)&Bls[r * 64 + (((half * 4 + g) ^ (r & 7)) << 3)];
      }
      __builtin_amdgcn_s_setprio(1);
#pragma unroll
      for (int mi = 0; mi < 4; mi++)
#pragma unroll
        for (int ni = 0; ni < 4; ni++)
          acc[mi][ni] = __builtin_amdgcn_mfma_f32_16x16x32_bf16(af[mi], bfr[ni],
                                                                acc[mi][ni], 0, 0, 0);
      __builtin_amdgcn_s_setprio(0);
    }
  }
#pragma unroll
  for (int mi = 0; mi < 4; mi++) {
#pragma unroll
    for (int ni = 0; ni < 4; ni++) {
      const int gn = n0 + wn * 64 + ni * 16 + c;
      const float bb = bias[gn];
      const int gmb = m0 + wm * 64 + mi * 16 + (g << 2);
      const int hd = gn >> 6, d = gn & 63;
      if (mode == 2) {
        const int b = gmb >> 11, s0 = gmb & 2047;
        const int tile = s0 >> 6;
        const int jb = gmb & 63;
        const int j5b = jb & 31;
        const int posb = ((jb >> 5) << 5) + (((j5b & 15) >> 2) << 3) + ((j5b >> 4) << 2);
        s16x4 st;
#pragma unroll
        for (int r = 0; r < 4; r++) st[r] = (short)f2bf(acc[mi][ni][r] + bb);
        *(s16x4*)&Vt[(((size_t)b * 16 + hd) * 64 + d) * 2048 + tile * 64 + posb] = st;
      } else {
#pragma unroll
        for (int r = 0; r < 4; r++) {
          const int gm = gmb + r;
          float val = acc[mi][ni][r] + bb;
          const int b = gm >> 11, s = gm & 2047;
          if (mode == 0) val *= 0.18033688f;  // 0.125 * log2(e)
          outp[(((size_t)b * 16 + hd) * 2048 + s) * 64 + d] = f2bf(val);
        }
      }
    }
  }
}

// ---------------- output GEMM: 128x64 tile, BK=64, XCD-swizzled ----------------
__global__ __launch_bounds__(256) void gemm_out(const u16* __restrict__ A,
                                                const u16* __restrict__ Bt,
                                                const float* __restrict__ bias,
                                                float* __restrict__ outp) {
  __shared__ u16 Als[128 * 64];
  __shared__ u16 Bls[64 * 64];
  const int tid = threadIdx.x;
  const int lane = tid & 63;
  const int wid = tid >> 6;
  const int sid = blockIdx.x + (blockIdx.y << 4);
  const int xcd = sid & 7, sj = sid >> 3;
  const int m0 = ((xcd << 2) + (sj & 3)) * 128;
  const int n0 = (sj >> 2) * 64;
  const int g = lane >> 4, c = lane & 15;
  const int srl = lane >> 3, sch0 = lane & 7;
  f32x4 acc[2][4] = {};
  for (int kk = 0; kk < 1024; kk += 64) {
    __syncthreads();
#pragma unroll
    for (int jj = 0; jj < 4; jj++) {
      const int rl = wid * 32 + jj * 8 + srl;
      const int col = kk + ((sch0 ^ (rl & 7)) << 3);
      __builtin_amdgcn_global_load_lds(AS1(A + (size_t)(m0 + rl) * 1024 + col),
                                       AS3(&Als[(wid * 32 + jj * 8) * 64]), 16, 0, 0);
    }
#pragma unroll
    for (int jj = 0; jj < 2; jj++) {
      const int rl = wid * 16 + jj * 8 + srl;
      const int col = kk + ((sch0 ^ (rl & 7)) << 3);
      __builtin_amdgcn_global_load_lds(AS1(Bt + (size_t)(n0 + rl) * 1024 + col),
                                       AS3(&Bls[(wid * 16 + jj * 8) * 64]), 16, 0, 0);
    }
    __syncthreads();
#pragma unroll
    for (int half = 0; half < 2; half++) {
      s16x8 af[2], bfr[4];
#pragma unroll
      for (int mi = 0; mi < 2; mi++) {
        const int r = wid * 32 + mi * 16 + c;
        af[mi] = *(const s16x8*)&Als[r * 64 + (((half * 4 + g) ^ (r & 7)) << 3)];
      }
#pragma unroll
      for (int ni = 0; ni < 4; ni++) {
        const int r = ni * 16 + c;
        bfr[ni] = *(const s16x8*)&Bls[r * 64 + (((half * 4 + g) ^ (r & 7)) << 3)];
      }
      __builtin_amdgcn_s_setprio(1);
#pragma unroll
      for (int mi = 0; mi < 2; mi++)
#pragma unroll
        for (int ni = 0; ni < 4; ni++)
          acc[mi][ni] = __builtin_amdgcn_mfma_f32_16x16x32_bf16(af[mi], bfr[ni],
                                                                acc[mi][ni], 0, 0, 0);
      __builtin_amdgcn_s_setprio(0);
    }
  }
#pragma unroll
  for (int mi = 0; mi < 2; mi++) {
#pragma unroll
    for (int ni = 0; ni < 4; ni++) {
      const int gn = n0 + ni * 16 + c;
      const float bb = bias[gn];
      const int gmb = m0 + wid * 32 + mi * 16 + (g << 2);
#pragma unroll
      for (int r = 0; r < 4; r++)
        outp[(size_t)(gmb + r) * 1024 + gn] = acc[mi][ni][r] + bb;
    }
  }
}

// ---------------- flash attention: counted-vmcnt + reg-only mask fast path, no Mls ----------------
// Masked path reads mask directly from global (L2-resident, scale folded via fmaf) —
// proven round-8 formulation. LDS = 32 KB -> 5 blocks/CU.
__global__ __launch_bounds__(128) void attn_fwd(const u16* __restrict__ Qb,
                                                const u16* __restrict__ Kb,
                                                const u16* __restrict__ Vt,
                                                const float* __restrict__ mask,
                                                u16* __restrict__ ctx) {
  __shared__ u16 Kls[2][4096];
  __shared__ u16 Vls[2][4096];
  const int tid = threadIdx.x;
  const int lane = tid & 63, wid = tid >> 6;  // wid 0..1
  const int n = blockIdx.x;
  const int bh = ((n & 7) << 2) | ((n >> 3) & 3);  // 4 bh per XCD
  const int qblk = n >> 5;                          // 0..31
  const int b = bh >> 4, hd = bh & 15;
  const int g = lane >> 4, c = lane & 15;
  const int qbase = qblk * 64 + wid * 32;

  // reg-only all-zero mask detection (full-row scan per wave -> wave-uniform)
  const float* mp = mask + (size_t)b * 2048;
  int th_any = 0;
#pragma unroll
  for (int i = 0; i < 8; i++) {
    const f32x4 m4 = *(const f32x4*)(mp + lane * 32 + i * 4);
    th_any |= (m4[0] != 0.f) | (m4[1] != 0.f) | (m4[2] != 0.f) | (m4[3] != 0.f);
  }
  const int havemask = (__ballot(th_any) != 0ULL);

  // Q fragments for both 16-q subtiles, hoisted
  s16x8 qf[2][2];
#pragma unroll
  for (int sub = 0; sub < 2; sub++) {
    const u16* Qp = Qb + ((size_t)bh * 2048 + qbase + sub * 16 + c) * 64;
    qf[sub][0] = *(const s16x8*)(Qp + g * 8);
    qf[sub][1] = *(const s16x8*)(Qp + 32 + g * 8);
  }

  const u16* Kbh = Kb + (size_t)bh * 2048 * 64;
  const u16* Vbh = Vt + (size_t)bh * 64 * 2048;

  const int srl = lane >> 3;
  const int sch0 = lane & 7;
  auto STAGE = [&](int kv0, int bufi) {
#pragma unroll
    for (int jj = 0; jj < 4; jj++) {
      const int rl = wid * 32 + jj * 8 + srl;
      const int sch = sch0 ^ (rl & 7);
      __builtin_amdgcn_global_load_lds(AS1(Kbh + (size_t)(kv0 + rl) * 64 + sch * 8),
                                       AS3(&Kls[bufi][wid * 2048 + jj * 512]), 16, 0, 0);
      __builtin_amdgcn_global_load_lds(AS1(Vbh + (size_t)rl * 2048 + kv0 + sch * 8),
                                       AS3(&Vls[bufi][wid * 2048 + jj * 512]), 16, 0, 0);
    }
  };

  f32x4 o[2][4] = {};
  f32x4 ts2[2] = {};

  STAGE(0, 0);
  STAGE(64, 1);

  for (int t = 0; t < 32; t++) {
    const int kv0 = t * 64;
    const int buf = t & 1;
    if (t < 31) {
      asm volatile("s_waitcnt vmcnt(8)" ::: "memory");
    } else {
      asm volatile("s_waitcnt vmcnt(0)" ::: "memory");
    }
    __builtin_amdgcn_sched_barrier(0);
    __builtin_amdgcn_s_barrier();
    __builtin_amdgcn_sched_barrier(0);

    // ---- QK^T: K fragment read once, used by both q-subtiles ----
    f32x4 sacc[2][4] = {};
#pragma unroll
    for (int kvt = 0; kvt < 4; kvt++) {
      const int row = kvt * 16 + c;
      const int s7 = row & 7;
      const s16x8 kf0 = *(const s16x8*)&Kls[buf][row * 64 + ((g ^ s7) << 3)];
      const s16x8 kf1 = *(const s16x8*)&Kls[buf][row * 64 + (((4 + g) ^ s7) << 3)];
      sacc[0][kvt] = __builtin_amdgcn_mfma_f32_16x16x32_bf16(kf0, qf[0][0], sacc[0][kvt], 0, 0, 0);
      sacc[0][kvt] = __builtin_amdgcn_mfma_f32_16x16x32_bf16(kf1, qf[0][1], sacc[0][kvt], 0, 0, 0);
      sacc[1][kvt] = __builtin_amdgcn_mfma_f32_16x16x32_bf16(kf0, qf[1][0], sacc[1][kvt], 0, 0, 0);
      sacc[1][kvt] = __builtin_amdgcn_mfma_f32_16x16x32_bf16(kf1, qf[1][1], sacc[1][kvt], 0, 0, 0);
    }

    // ---- V fragments -> regs (shared by both q-subtiles) ----
    s16x8 vreg[4][2];
#pragma unroll
    for (int dblk = 0; dblk < 4; dblk++) {
      const int row = dblk * 16 + c;
      const int s7 = row & 7;
      const u16* base = &Vls[buf][row * 64];
      vreg[dblk][0] = *(const s16x8*)(base + ((g ^ s7) << 3));
      vreg[dblk][1] = *(const s16x8*)(base + (((4 + g) ^ s7) << 3));
    }
    // ---- release: all reads of buf done across block -> safe to restage ----
    asm volatile("s_waitcnt lgkmcnt(0)" ::: "memory");
    __builtin_amdgcn_sched_barrier(0);
    __builtin_amdgcn_s_barrier();
    __builtin_amdgcn_sched_barrier(0);
    if (t < 30) STAGE(kv0 + 128, buf);

    // ---- softmax: reg-only fast path (mask all zero) or global-mask path ----
    s16x8 pf[2][2];
    if (!havemask) {
#pragma unroll
      for (int qs = 0; qs < 2; qs++) {
        f32x4 p4[4];
#pragma unroll
        for (int kvt = 0; kvt < 4; kvt++) {
#pragma unroll
          for (int jj = 0; jj < 4; jj++)
            p4[kvt][jj] = __builtin_amdgcn_exp2f(sacc[qs][kvt][jj]);
          ts2[qs] += p4[kvt];
        }
#pragma unroll
        for (int sub = 0; sub < 2; sub++) {
          u32x4 ww;
          ww[0] = cvtpk(p4[sub * 2][0], p4[sub * 2][1]);
          ww[1] = cvtpk(p4[sub * 2][2], p4[sub * 2][3]);
          ww[2] = cvtpk(p4[sub * 2 + 1][0], p4[sub * 2 + 1][1]);
          ww[3] = cvtpk(p4[sub * 2 + 1][2], p4[sub * 2 + 1][3]);
          pf[qs][sub] = __builtin_bit_cast(s16x8, ww);
        }
      }
    } else {
      f32x4 mk[4];
#pragma unroll
      for (int kvt = 0; kvt < 4; kvt++)
        mk[kvt] = *(const f32x4*)(mp + kv0 + kvt * 16 + 4 * g);
#pragma unroll
      for (int qs = 0; qs < 2; qs++) {
        f32x4 p4[4];
#pragma unroll
        for (int kvt = 0; kvt < 4; kvt++) {
#pragma unroll
          for (int jj = 0; jj < 4; jj++)
            p4[kvt][jj] = __builtin_amdgcn_exp2f(fmaf(mk[kvt][jj], -1.44269504e9f,
                                                      sacc[qs][kvt][jj]));
          ts2[qs] += p4[kvt];
        }
#pragma unroll
        for (int sub = 0; sub < 2; sub++) {
          u32x4 ww;
          ww[0] = cvtpk(p4[sub * 2][0], p4[sub * 2][1]);
          ww[1] = cvtpk(p4[sub * 2][2], p4[sub * 2][3]);
          ww[2] = cvtpk(p4[sub * 2 + 1][0], p4[sub * 2 + 1][1]);
          ww[3] = cvtpk(p4[sub * 2 + 1][2], p4[sub * 2 + 1][3]);
          pf[qs][sub] = __builtin_bit_cast(s16x8, ww);
        }
      }
    }

    // ---- PV from registers ----
#pragma unroll
    for (int dblk = 0; dblk < 4; dblk++)
#pragma unroll
      for (int subk = 0; subk < 2; subk++) {
        o[0][dblk] = __builtin_amdgcn_mfma_f32_16x16x32_bf16(vreg[dblk][subk], pf[0][subk], o[0][dblk], 0, 0, 0);
        o[1][dblk] = __builtin_amdgcn_mfma_f32_16x16x32_bf16(vreg[dblk][subk], pf[1][subk], o[1][dblk], 0, 0, 0);
      }
  }

#pragma unroll
  for (int qs = 0; qs < 2; qs++) {
    float ts = (ts2[qs][0] + ts2[qs][1]) + (ts2[qs][2] + ts2[qs][3]);
    ts += __shfl_xor(ts, 16);
    ts += __shfl_xor(ts, 32);
    const float inv = 1.0f / ts;
    u16* cp = ctx + ((size_t)b * 2048 + qbase + qs * 16 + c) * 1024 + hd * 64;
#pragma unroll
    for (int d = 0; d < 4; d++) {
      u32x2 st;
      st[0] = cvtpk(o[qs][d][0] * inv, o[qs][d][1] * inv);
      st[1] = cvtpk(o[qs][d][2] * inv, o[qs][d][3] * inv);
      *(u32x2*)&cp[d * 16 + 4 * g] = st;
    }
  }
}

extern "C" void kernel_launch(void* const* d_in, const int* in_sizes, int n_in,
                              void* d_out, int out_size, void* d_ws, size_t ws_size,
                              hipStream_t stream) {
  (void)in_sizes; (void)n_in; (void)out_size; (void)ws_size;
  const float* q = (const float*)d_in[0];
  const float* k = (const float*)d_in[1];
  const float* v = (const float*)d_in[2];
  const float* mask = (const float*)d_in[3];
  const float* wq = (const float*)d_in[4];
  const float* bq = (const float*)d_in[5];
  const float* wk = (const float*)d_in[6];
  const float* bk = (const float*)d_in[7];
  const float* wv = (const float*)d_in[8];
  const float* bv = (const float*)d_in[9];
  const float* wo = (const float*)d_in[10];
  const float* bo = (const float*)d_in[11];
  float* out = (float*)d_out;
  char* ws = (char*)d_ws;
  const size_t MB = (size_t)1 << 20;
  u16* Xq = (u16*)(ws + 0 * MB);
  u16* Xk = (u16*)(ws + 8 * MB);
  u16* Xv = (u16*)(ws + 16 * MB);
  u16* Wqt = (u16*)(ws + 24 * MB);
  u16* Wkt = (u16*)(ws + 26 * MB);
  u16* Wvt = (u16*)(ws + 28 * MB);
  u16* Wot = (u16*)(ws + 30 * MB);
  u16* Qb = (u16*)(ws + 32 * MB);
  u16* Kb = (u16*)(ws + 40 * MB);
  u16* Vt = (u16*)(ws + 48 * MB);
  u16* ctx = Xq;  // alias: Xq dead once attn runs

  prep<<<10240, 256, 0, stream>>>(q, k, v, wq, wk, wv, wo, Xq, Xk, Xv, Wqt, Wkt, Wvt, Wot);
  gemm_qkv<<<dim3(8, 32, 3), 256, 0, stream>>>(Xq, Xk, Xv, Wqt, Wkt, Wvt, bq, bk, bv,
                                               Qb, Kb, Vt);
  attn_fwd<<<1024, 128, 0, stream>>>(Qb, Kb, Vt, mask, ctx);
  gemm_out<<<dim3(16, 32), 256, 0, stream>>>(ctx, Wot, bo, out);
}

// Round 22
// 120.766 us; speedup vs baseline: 1.0789x; 1.0498x over previous
//
#include <hip/hip_runtime.h>
#include <hip/hip_bf16.h>

typedef unsigned short u16;
typedef __attribute__((ext_vector_type(8))) short s16x8;
typedef __attribute__((ext_vector_type(4))) short s16x4;
typedef __attribute__((ext_vector_type(4))) float f32x4;
typedef __attribute__((ext_vector_type(8))) unsigned short u16x8;
typedef __attribute__((ext_vector_type(4))) unsigned int u32x4;
typedef __attribute__((ext_vector_type(2))) unsigned int u32x2;

#define AS1(p) (const __attribute__((address_space(1))) void*)(p)
#define AS3(p) (__attribute__((address_space(3))) void*)(p)

__device__ __forceinline__ u16 f2bf(float f) {
  unsigned u = __builtin_bit_cast(unsigned, f);
  u += 0x7fffu + ((u >> 16) & 1u);
  return (u16)(u >> 16);
}

__device__ __forceinline__ unsigned cvtpk(float lo, float hi) {
  unsigned r;
  asm("v_cvt_pk_bf16_f32 %0, %1, %2" : "=v"(r) : "v"(lo), "v"(hi));
  return r;
}

// ------------- fused prep: cvt q/k/v -> bf16  +  transpose 4 weights -------------
__global__ __launch_bounds__(256) void prep(const float* __restrict__ q,
                                            const float* __restrict__ k,
                                            const float* __restrict__ v,
                                            const float* __restrict__ wq,
                                            const float* __restrict__ wk,
                                            const float* __restrict__ wv,
                                            const float* __restrict__ wo,
                                            u16* __restrict__ Xq, u16* __restrict__ Xk,
                                            u16* __restrict__ Xv, u16* __restrict__ Wqt,
                                            u16* __restrict__ Wkt, u16* __restrict__ Wvt,
                                            u16* __restrict__ Wot) {
  __shared__ float t[32][33];
  const int bid = blockIdx.x, tid = threadIdx.x;
  if (bid < 6144) {
    const int m = bid >> 11;
    const float* in = m == 0 ? q : m == 1 ? k : v;
    u16* out = m == 0 ? Xq : m == 1 ? Xk : Xv;
    const int i = ((bid & 2047) * 256 + tid) * 8;
    f32x4 a = *(const f32x4*)(in + i);
    f32x4 b = *(const f32x4*)(in + i + 4);
    u16x8 r;
    r[0] = f2bf(a[0]); r[1] = f2bf(a[1]); r[2] = f2bf(a[2]); r[3] = f2bf(a[3]);
    r[4] = f2bf(b[0]); r[5] = f2bf(b[1]); r[6] = f2bf(b[2]); r[7] = f2bf(b[3]);
    *(u16x8*)(out + i) = r;
  } else {
    const int b2 = bid - 6144;
    const int wsel = b2 >> 10;
    const float* w = wsel == 0 ? wq : wsel == 1 ? wk : wsel == 2 ? wv : wo;
    u16* wt = wsel == 0 ? Wqt : wsel == 1 ? Wkt : wsel == 2 ? Wvt : Wot;
    const int n0 = (b2 & 31) * 32, k0 = ((b2 >> 5) & 31) * 32;
    const int tx = tid & 31, ty = tid >> 5;
#pragma unroll
    for (int i = 0; i < 4; i++)
      t[ty + 8 * i][tx] = w[(size_t)(k0 + ty + 8 * i) * 1024 + n0 + tx];
    __syncthreads();
#pragma unroll
    for (int i = 0; i < 4; i++)
      wt[(size_t)(n0 + ty + 8 * i) * 1024 + k0 + tx] = f2bf(t[tx][ty + 8 * i]);
  }
}

// ---- fused QKV GEMM: BK=32, double-buffered LDS, counted-vmcnt pipeline, XCD-swizzled ----
// Protocol (attn-proven since r13): acquire = vmcnt(4)+barrier (next-tile loads stay in
// flight); fragments -> regs; release = lgkmcnt(0)+barrier; STAGE(k+2); MFMA.
__global__ __launch_bounds__(256) void gemm_qkv(const u16* __restrict__ Xq,
                                                const u16* __restrict__ Xk,
                                                const u16* __restrict__ Xv,
                                                const u16* __restrict__ Wqt,
                                                const u16* __restrict__ Wkt,
                                                const u16* __restrict__ Wvt,
                                                const float* __restrict__ bq,
                                                const float* __restrict__ bk,
                                                const float* __restrict__ bv,
                                                u16* __restrict__ Qb, u16* __restrict__ Kb,
                                                u16* __restrict__ Vt) {
  const int mode = blockIdx.z;
  const u16* A = mode == 0 ? Xq : mode == 1 ? Xk : Xv;
  const u16* Bt = mode == 0 ? Wqt : mode == 1 ? Wkt : Wvt;
  const float* bias = mode == 0 ? bq : mode == 1 ? bk : bv;
  u16* outp = mode == 0 ? Qb : mode == 1 ? Kb : Vt;

  __shared__ u16 Als[2][128 * 32];
  __shared__ u16 Bls[2][128 * 32];
  const int tid = threadIdx.x;
  const int lane = tid & 63;
  const int wid = tid >> 6;
  const int wm = wid >> 1, wn = wid & 1;
  const int sid = blockIdx.x + (blockIdx.y << 3);
  const int xcd = sid & 7, sj = sid >> 3;
  const int m0 = ((xcd << 2) + (sj & 3)) * 128;
  const int n0 = (sj >> 2) * 128;
  const int g = lane >> 4, c = lane & 15;
  const int srow = lane >> 2, schunk = lane & 3;

  auto STAGE = [&](int kk, int bufi) {
#pragma unroll
    for (int i = 0; i < 2; i++) {
      const int row = i * 64 + wid * 16 + srow;
      const int col = kk + ((schunk ^ (row & 3)) << 3);
      __builtin_amdgcn_global_load_lds(AS1(A + (size_t)(m0 + row) * 1024 + col),
                                       AS3(&Als[bufi][(i * 64 + wid * 16) * 32]), 16, 0, 0);
      __builtin_amdgcn_global_load_lds(AS1(Bt + (size_t)(n0 + row) * 1024 + col),
                                       AS3(&Bls[bufi][(i * 64 + wid * 16) * 32]), 16, 0, 0);
    }
  };

  f32x4 acc[4][4] = {};
  STAGE(0, 0);
  STAGE(32, 1);
  for (int t = 0; t < 32; t++) {
    const int buf = t & 1;
    if (t < 31) {
      asm volatile("s_waitcnt vmcnt(4)" ::: "memory");
    } else {
      asm volatile("s_waitcnt vmcnt(0)" ::: "memory");
    }
    __builtin_amdgcn_sched_barrier(0);
    __builtin_amdgcn_s_barrier();
    __builtin_amdgcn_sched_barrier(0);
    s16x8 af[4], bfr[4];
#pragma unroll
    for (int mi = 0; mi < 4; mi++) {
      const int r = wm * 64 + mi * 16 + c;
      af[mi] = *(const s16x8*)&Als[buf][r * 32 + ((g ^ (r & 3)) << 3)];
    }
#pragma unroll
    for (int ni = 0; ni < 4; ni++) {
      const int r = wn * 64 + ni * 16 + c;
      bfr[ni] = *(const s16x8*)&Bls[buf][r * 32 + ((g ^ (r & 3)) << 3)];
    }
    asm volatile("s_waitcnt lgkmcnt(0)" ::: "memory");
    __builtin_amdgcn_sched_barrier(0);
    __builtin_amdgcn_s_barrier();
    __builtin_amdgcn_sched_barrier(0);
    if (t < 30) STAGE((t + 2) * 32, buf);
    __builtin_amdgcn_s_setprio(1);
#pragma unroll
    for (int mi = 0; mi < 4; mi++)
#pragma unroll
      for (int ni = 0; ni < 4; ni++)
        acc[mi][ni] = __builtin_amdgcn_mfma_f32_16x16x32_bf16(af[mi], bfr[ni],
                                                              acc[mi][ni], 0, 0, 0);
    __builtin_amdgcn_s_setprio(0);
  }
#pragma unroll
  for (int mi = 0; mi < 4; mi++) {
#pragma unroll
    for (int ni = 0; ni < 4; ni++) {
      const int gn = n0 + wn * 64 + ni * 16 + c;
      const float bb = bias[gn];
      const int gmb = m0 + wm * 64 + mi * 16 + (g << 2);
      const int hd = gn >> 6, d = gn & 63;
      if (mode == 2) {
        const int b = gmb >> 11, s0 = gmb & 2047;
        const int tile = s0 >> 6;
        const int jb = gmb & 63;
        const int j5b = jb & 31;
        const int posb = ((jb >> 5) << 5) + (((j5b & 15) >> 2) << 3) + ((j5b >> 4) << 2);
        s16x4 st;
#pragma unroll
        for (int r = 0; r < 4; r++) st[r] = (short)f2bf(acc[mi][ni][r] + bb);
        *(s16x4*)&Vt[(((size_t)b * 16 + hd) * 64 + d) * 2048 + tile * 64 + posb] = st;
      } else {
#pragma unroll
        for (int r = 0; r < 4; r++) {
          const int gm = gmb + r;
          float val = acc[mi][ni][r] + bb;
          const int b = gm >> 11, s = gm & 2047;
          if (mode == 0) val *= 0.18033688f;  // 0.125 * log2(e)
          outp[(((size_t)b * 16 + hd) * 2048 + s) * 64 + d] = f2bf(val);
        }
      }
    }
  }
}

// ---------------- output GEMM: 128x64, BK=32 dbuf counted-vmcnt, XCD-swizzled ----------------
__global__ __launch_bounds__(256) void gemm_out(const u16* __restrict__ A,
                                                const u16* __restrict__ Bt,
                                                const float* __restrict__ bias,
                                                float* __restrict__ outp) {
  __shared__ u16 Als[2][128 * 32];
  __shared__ u16 Bls[2][64 * 32];
  const int tid = threadIdx.x;
  const int lane = tid & 63;
  const int wid = tid >> 6;
  const int sid = blockIdx.x + (blockIdx.y << 4);
  const int xcd = sid & 7, sj = sid >> 3;
  const int m0 = ((xcd << 2) + (sj & 3)) * 128;
  const int n0 = (sj >> 2) * 64;
  const int g = lane >> 4, c = lane & 15;
  const int srow = lane >> 2, schunk = lane & 3;

  auto STAGE = [&](int kk, int bufi) {
#pragma unroll
    for (int i = 0; i < 2; i++) {
      const int row = i * 64 + wid * 16 + srow;
      const int col = kk + ((schunk ^ (row & 3)) << 3);
      __builtin_amdgcn_global_load_lds(AS1(A + (size_t)(m0 + row) * 1024 + col),
                                       AS3(&Als[bufi][(i * 64 + wid * 16) * 32]), 16, 0, 0);
    }
    {
      const int row = wid * 16 + srow;
      const int col = kk + ((schunk ^ (row & 3)) << 3);
      __builtin_amdgcn_global_load_lds(AS1(Bt + (size_t)(n0 + row) * 1024 + col),
                                       AS3(&Bls[bufi][(wid * 16) * 32]), 16, 0, 0);
    }
  };

  f32x4 acc[2][4] = {};
  STAGE(0, 0);
  STAGE(32, 1);
  for (int t = 0; t < 32; t++) {
    const int buf = t & 1;
    if (t < 31) {
      asm volatile("s_waitcnt vmcnt(3)" ::: "memory");
    } else {
      asm volatile("s_waitcnt vmcnt(0)" ::: "memory");
    }
    __builtin_amdgcn_sched_barrier(0);
    __builtin_amdgcn_s_barrier();
    __builtin_amdgcn_sched_barrier(0);
    s16x8 af[2], bfr[4];
#pragma unroll
    for (int mi = 0; mi < 2; mi++) {
      const int r = wid * 32 + mi * 16 + c;
      af[mi] = *(const s16x8*)&Als[buf][r * 32 + ((g ^ (r & 3)) << 3)];
    }
#pragma unroll
    for (int ni = 0; ni < 4; ni++) {
      const int r = ni * 16 + c;
      bfr[ni] = *(const s16x8*)&Bls[buf][r * 32 + ((g ^ (r & 3)) << 3)];
    }
    asm volatile("s_waitcnt lgkmcnt(0)" ::: "memory");
    __builtin_amdgcn_sched_barrier(0);
    __builtin_amdgcn_s_barrier();
    __builtin_amdgcn_sched_barrier(0);
    if (t < 30) STAGE((t + 2) * 32, buf);
    __builtin_amdgcn_s_setprio(1);
#pragma unroll
    for (int mi = 0; mi < 2; mi++)
#pragma unroll
      for (int ni = 0; ni < 4; ni++)
        acc[mi][ni] = __builtin_amdgcn_mfma_f32_16x16x32_bf16(af[mi], bfr[ni],
                                                              acc[mi][ni], 0, 0, 0);
    __builtin_amdgcn_s_setprio(0);
  }
#pragma unroll
  for (int mi = 0; mi < 2; mi++) {
#pragma unroll
    for (int ni = 0; ni < 4; ni++) {
      const int gn = n0 + ni * 16 + c;
      const float bb = bias[gn];
      const int gmb = m0 + wid * 32 + mi * 16 + (g << 2);
#pragma unroll
      for (int r = 0; r < 4; r++)
        outp[(size_t)(gmb + r) * 1024 + gn] = acc[mi][ni][r] + bb;
    }
  }
}

// ---------------- flash attention: counted-vmcnt + reg-only mask fast path (r21) ----------------
__global__ __launch_bounds__(128) void attn_fwd(const u16* __restrict__ Qb,
                                                const u16* __restrict__ Kb,
                                                const u16* __restrict__ Vt,
                                                const float* __restrict__ mask,
                                                u16* __restrict__ ctx) {
  __shared__ u16 Kls[2][4096];
  __shared__ u16 Vls[2][4096];
  const int tid = threadIdx.x;
  const int lane = tid & 63, wid = tid >> 6;  // wid 0..1
  const int n = blockIdx.x;
  const int bh = ((n & 7) << 2) | ((n >> 3) & 3);  // 4 bh per XCD
  const int qblk = n >> 5;                          // 0..31
  const int b = bh >> 4, hd = bh & 15;
  const int g = lane >> 4, c = lane & 15;
  const int qbase = qblk * 64 + wid * 32;

  // reg-only all-zero mask detection (full-row scan per wave -> wave-uniform)
  const float* mp = mask + (size_t)b * 2048;
  int th_any = 0;
#pragma unroll
  for (int i = 0; i < 8; i++) {
    const f32x4 m4 = *(const f32x4*)(mp + lane * 32 + i * 4);
    th_any |= (m4[0] != 0.f) | (m4[1] != 0.f) | (m4[2] != 0.f) | (m4[3] != 0.f);
  }
  const int havemask = (__ballot(th_any) != 0ULL);

  // Q fragments for both 16-q subtiles, hoisted
  s16x8 qf[2][2];
#pragma unroll
  for (int sub = 0; sub < 2; sub++) {
    const u16* Qp = Qb + ((size_t)bh * 2048 + qbase + sub * 16 + c) * 64;
    qf[sub][0] = *(const s16x8*)(Qp + g * 8);
    qf[sub][1] = *(const s16x8*)(Qp + 32 + g * 8);
  }

  const u16* Kbh = Kb + (size_t)bh * 2048 * 64;
  const u16* Vbh = Vt + (size_t)bh * 64 * 2048;

  const int srl = lane >> 3;
  const int sch0 = lane & 7;
  auto STAGE = [&](int kv0, int bufi) {
#pragma unroll
    for (int jj = 0; jj < 4; jj++) {
      const int rl = wid * 32 + jj * 8 + srl;
      const int sch = sch0 ^ (rl & 7);
      __builtin_amdgcn_global_load_lds(AS1(Kbh + (size_t)(kv0 + rl) * 64 + sch * 8),
                                       AS3(&Kls[bufi][wid * 2048 + jj * 512]), 16, 0, 0);
      __builtin_amdgcn_global_load_lds(AS1(Vbh + (size_t)rl * 2048 + kv0 + sch * 8),
                                       AS3(&Vls[bufi][wid * 2048 + jj * 512]), 16, 0, 0);
    }
  };

  f32x4 o[2][4] = {};
  f32x4 ts2[2] = {};

  STAGE(0, 0);
  STAGE(64, 1);

  for (int t = 0; t < 32; t++) {
    const int kv0 = t * 64;
    const int buf = t & 1;
    if (t < 31) {
      asm volatile("s_waitcnt vmcnt(8)" ::: "memory");
    } else {
      asm volatile("s_waitcnt vmcnt(0)" ::: "memory");
    }
    __builtin_amdgcn_sched_barrier(0);
    __builtin_amdgcn_s_barrier();
    __builtin_amdgcn_sched_barrier(0);

    // ---- QK^T: K fragment read once, used by both q-subtiles ----
    f32x4 sacc[2][4] = {};
#pragma unroll
    for (int kvt = 0; kvt < 4; kvt++) {
      const int row = kvt * 16 + c;
      const int s7 = row & 7;
      const s16x8 kf0 = *(const s16x8*)&Kls[buf][row * 64 + ((g ^ s7) << 3)];
      const s16x8 kf1 = *(const s16x8*)&Kls[buf][row * 64 + (((4 + g) ^ s7) << 3)];
      sacc[0][kvt] = __builtin_amdgcn_mfma_f32_16x16x32_bf16(kf0, qf[0][0], sacc[0][kvt], 0, 0, 0);
      sacc[0][kvt] = __builtin_amdgcn_mfma_f32_16x16x32_bf16(kf1, qf[0][1], sacc[0][kvt], 0, 0, 0);
      sacc[1][kvt] = __builtin_amdgcn_mfma_f32_16x16x32_bf16(kf0, qf[1][0], sacc[1][kvt], 0, 0, 0);
      sacc[1][kvt] = __builtin_amdgcn_mfma_f32_16x16x32_bf16(kf1, qf[1][1], sacc[1][kvt], 0, 0, 0);
    }

    // ---- V fragments -> regs (shared by both q-subtiles) ----
    s16x8 vreg[4][2];
#pragma unroll
    for (int dblk = 0; dblk < 4; dblk++) {
      const int row = dblk * 16 + c;
      const int s7 = row & 7;
      const u16* base = &Vls[buf][row * 64];
      vreg[dblk][0] = *(const s16x8*)(base + ((g ^ s7) << 3));
      vreg[dblk][1] = *(const s16x8*)(base + (((4 + g) ^ s7) << 3));
    }
    // ---- release: all reads of buf done across block -> safe to restage ----
    asm volatile("s_waitcnt lgkmcnt(0)" ::: "memory");
    __builtin_amdgcn_sched_barrier(0);
    __builtin_amdgcn_s_barrier();
    __builtin_amdgcn_sched_barrier(0);
    if (t < 30) STAGE(kv0 + 128, buf);

    // ---- softmax: reg-only fast path (mask all zero) or global-mask path ----
    s16x8 pf[2][2];
    if (!havemask) {
#pragma unroll
      for (int qs = 0; qs < 2; qs++) {
        f32x4 p4[4];
#pragma unroll
        for (int kvt = 0; kvt < 4; kvt++) {
#pragma unroll
          for (int jj = 0; jj < 4; jj++)
            p4[kvt][jj] = __builtin_amdgcn_exp2f(sacc[qs][kvt][jj]);
          ts2[qs] += p4[kvt];
        }
#pragma unroll
        for (int sub = 0; sub < 2; sub++) {
          u32x4 ww;
          ww[0] = cvtpk(p4[sub * 2][0], p4[sub * 2][1]);
          ww[1] = cvtpk(p4[sub * 2][2], p4[sub * 2][3]);
          ww[2] = cvtpk(p4[sub * 2 + 1][0], p4[sub * 2 + 1][1]);
          ww[3] = cvtpk(p4[sub * 2 + 1][2], p4[sub * 2 + 1][3]);
          pf[qs][sub] = __builtin_bit_cast(s16x8, ww);
        }
      }
    } else {
      f32x4 mk[4];
#pragma unroll
      for (int kvt = 0; kvt < 4; kvt++)
        mk[kvt] = *(const f32x4*)(mp + kv0 + kvt * 16 + 4 * g);
#pragma unroll
      for (int qs = 0; qs < 2; qs++) {
        f32x4 p4[4];
#pragma unroll
        for (int kvt = 0; kvt < 4; kvt++) {
#pragma unroll
          for (int jj = 0; jj < 4; jj++)
            p4[kvt][jj] = __builtin_amdgcn_exp2f(fmaf(mk[kvt][jj], -1.44269504e9f,
                                                      sacc[qs][kvt][jj]));
          ts2[qs] += p4[kvt];
        }
#pragma unroll
        for (int sub = 0; sub < 2; sub++) {
          u32x4 ww;
          ww[0] = cvtpk(p4[sub * 2][0], p4[sub * 2][1]);
          ww[1] = cvtpk(p4[sub * 2][2], p4[sub * 2][3]);
          ww[2] = cvtpk(p4[sub * 2 + 1][0], p4[sub * 2 + 1][1]);
          ww[3] = cvtpk(p4[sub * 2 + 1][2], p4[sub * 2 + 1][3]);
          pf[qs][sub] = __builtin_bit_cast(s16x8, ww);
        }
      }
    }

    // ---- PV from registers ----
#pragma unroll
    for (int dblk = 0; dblk < 4; dblk++)
#pragma unroll
      for (int subk = 0; subk < 2; subk++) {
        o[0][dblk] = __builtin_amdgcn_mfma_f32_16x16x32_bf16(vreg[dblk][subk], pf[0][subk], o[0][dblk], 0, 0, 0);
        o[1][dblk] = __builtin_amdgcn_mfma_f32_16x16x32_bf16(vreg[dblk][subk], pf[1][subk], o[1][dblk], 0, 0, 0);
      }
  }

#pragma unroll
  for (int qs = 0; qs < 2; qs++) {
    float ts = (ts2[qs][0] + ts2[qs][1]) + (ts2[qs][2] + ts2[qs][3]);
    ts += __shfl_xor(ts, 16);
    ts += __shfl_xor(ts, 32);
    const float inv = 1.0f / ts;
    u16* cp = ctx + ((size_t)b * 2048 + qbase + qs * 16 + c) * 1024 + hd * 64;
#pragma unroll
    for (int d = 0; d < 4; d++) {
      u32x2 st;
      st[0] = cvtpk(o[qs][d][0] * inv, o[qs][d][1] * inv);
      st[1] = cvtpk(o[qs][d][2] * inv, o[qs][d][3] * inv);
      *(u32x2*)&cp[d * 16 + 4 * g] = st;
    }
  }
}

extern "C" void kernel_launch(void* const* d_in, const int* in_sizes, int n_in,
                              void* d_out, int out_size, void* d_ws, size_t ws_size,
                              hipStream_t stream) {
  (void)in_sizes; (void)n_in; (void)out_size; (void)ws_size;
  const float* q = (const float*)d_in[0];
  const float* k = (const float*)d_in[1];
  const float* v = (const float*)d_in[2];
  const float* mask = (const float*)d_in[3];
  const float* wq = (const float*)d_in[4];
  const float* bq = (const float*)d_in[5];
  const float* wk = (const float*)d_in[6];
  const float* bk = (const float*)d_in[7];
  const float* wv = (const float*)d_in[8];
  const float* bv = (const float*)d_in[9];
  const float* wo = (const float*)d_in[10];
  const float* bo = (const float*)d_in[11];
  float* out = (float*)d_out;
  char* ws = (char*)d_ws;
  const size_t MB = (size_t)1 << 20;
  u16* Xq = (u16*)(ws + 0 * MB);
  u16* Xk = (u16*)(ws + 8 * MB);
  u16* Xv = (u16*)(ws + 16 * MB);
  u16* Wqt = (u16*)(ws + 24 * MB);
  u16* Wkt = (u16*)(ws + 26 * MB);
  u16* Wvt = (u16*)(ws + 28 * MB);
  u16* Wot = (u16*)(ws + 30 * MB);
  u16* Qb = (u16*)(ws + 32 * MB);
  u16* Kb = (u16*)(ws + 40 * MB);
  u16* Vt = (u16*)(ws + 48 * MB);
  u16* ctx = Xq;  // alias: Xq dead once attn runs

  prep<<<10240, 256, 0, stream>>>(q, k, v, wq, wk, wv, wo, Xq, Xk, Xv, Wqt, Wkt, Wvt, Wot);
  gemm_qkv<<<dim3(8, 32, 3), 256, 0, stream>>>(Xq, Xk, Xv, Wqt, Wkt, Wvt, bq, bk, bv,
                                               Qb, Kb, Vt);
  attn_fwd<<<1024, 128, 0, stream>>>(Qb, Kb, Vt, mask, ctx);
  gemm_out<<<dim3(16, 32), 256, 0, stream>>>(ctx, Wot, bo, out);
}

// Round 23
// 118.903 us; speedup vs baseline: 1.0958x; 1.0157x over previous
//
#include <hip/hip_runtime.h>
#include <hip/hip_bf16.h>

typedef unsigned short u16;
typedef __attribute__((ext_vector_type(8))) short s16x8;
typedef __attribute__((ext_vector_type(4))) short s16x4;
typedef __attribute__((ext_vector_type(4))) float f32x4;
typedef __attribute__((ext_vector_type(8))) unsigned short u16x8;
typedef __attribute__((ext_vector_type(4))) unsigned int u32x4;
typedef __attribute__((ext_vector_type(2))) unsigned int u32x2;

#define AS1(p) (const __attribute__((address_space(1))) void*)(p)
#define AS3(p) (__attribute__((address_space(3))) void*)(p)

__device__ __forceinline__ u16 f2bf(float f) {
  unsigned u = __builtin_bit_cast(unsigned, f);
  u += 0x7fffu + ((u >> 16) & 1u);
  return (u16)(u >> 16);
}

__device__ __forceinline__ unsigned cvtpk(float lo, float hi) {
  unsigned r;
  asm("v_cvt_pk_bf16_f32 %0, %1, %2" : "=v"(r) : "v"(lo), "v"(hi));
  return r;
}

// ------------- fused prep: cvt q/k/v -> bf16  +  transpose 4 weights -------------
__global__ __launch_bounds__(256) void prep(const float* __restrict__ q,
                                            const float* __restrict__ k,
                                            const float* __restrict__ v,
                                            const float* __restrict__ wq,
                                            const float* __restrict__ wk,
                                            const float* __restrict__ wv,
                                            const float* __restrict__ wo,
                                            u16* __restrict__ Xq, u16* __restrict__ Xk,
                                            u16* __restrict__ Xv, u16* __restrict__ Wqt,
                                            u16* __restrict__ Wkt, u16* __restrict__ Wvt,
                                            u16* __restrict__ Wot) {
  __shared__ float t[32][33];
  const int bid = blockIdx.x, tid = threadIdx.x;
  if (bid < 6144) {
    const int m = bid >> 11;
    const float* in = m == 0 ? q : m == 1 ? k : v;
    u16* out = m == 0 ? Xq : m == 1 ? Xk : Xv;
    const int i = ((bid & 2047) * 256 + tid) * 8;
    f32x4 a = *(const f32x4*)(in + i);
    f32x4 b = *(const f32x4*)(in + i + 4);
    u16x8 r;
    r[0] = f2bf(a[0]); r[1] = f2bf(a[1]); r[2] = f2bf(a[2]); r[3] = f2bf(a[3]);
    r[4] = f2bf(b[0]); r[5] = f2bf(b[1]); r[6] = f2bf(b[2]); r[7] = f2bf(b[3]);
    *(u16x8*)(out + i) = r;
  } else {
    const int b2 = bid - 6144;
    const int wsel = b2 >> 10;
    const float* w = wsel == 0 ? wq : wsel == 1 ? wk : wsel == 2 ? wv : wo;
    u16* wt = wsel == 0 ? Wqt : wsel == 1 ? Wkt : wsel == 2 ? Wvt : Wot;
    const int n0 = (b2 & 31) * 32, k0 = ((b2 >> 5) & 31) * 32;
    const int tx = tid & 31, ty = tid >> 5;
#pragma unroll
    for (int i = 0; i < 4; i++)
      t[ty + 8 * i][tx] = w[(size_t)(k0 + ty + 8 * i) * 1024 + n0 + tx];
    __syncthreads();
#pragma unroll
    for (int i = 0; i < 4; i++)
      wt[(size_t)(n0 + ty + 8 * i) * 1024 + k0 + tx] = f2bf(t[tx][ty + 8 * i]);
  }
}

// ---- fused QKV GEMM: BK=32, double-buffered LDS, counted-vmcnt pipeline, XCD-swizzled ----
__global__ __launch_bounds__(256) void gemm_qkv(const u16* __restrict__ Xq,
                                                const u16* __restrict__ Xk,
                                                const u16* __restrict__ Xv,
                                                const u16* __restrict__ Wqt,
                                                const u16* __restrict__ Wkt,
                                                const u16* __restrict__ Wvt,
                                                const float* __restrict__ bq,
                                                const float* __restrict__ bk,
                                                const float* __restrict__ bv,
                                                u16* __restrict__ Qb, u16* __restrict__ Kb,
                                                u16* __restrict__ Vt) {
  const int mode = blockIdx.z;
  const u16* A = mode == 0 ? Xq : mode == 1 ? Xk : Xv;
  const u16* Bt = mode == 0 ? Wqt : mode == 1 ? Wkt : Wvt;
  const float* bias = mode == 0 ? bq : mode == 1 ? bk : bv;
  u16* outp = mode == 0 ? Qb : mode == 1 ? Kb : Vt;

  __shared__ u16 Als[2][128 * 32];
  __shared__ u16 Bls[2][128 * 32];
  const int tid = threadIdx.x;
  const int lane = tid & 63;
  const int wid = tid >> 6;
  const int wm = wid >> 1, wn = wid & 1;
  const int sid = blockIdx.x + (blockIdx.y << 3);
  const int xcd = sid & 7, sj = sid >> 3;
  const int m0 = ((xcd << 2) + (sj & 3)) * 128;
  const int n0 = (sj >> 2) * 128;
  const int g = lane >> 4, c = lane & 15;
  const int srow = lane >> 2, schunk = lane & 3;

  auto STAGE = [&](int kk, int bufi) {
#pragma unroll
    for (int i = 0; i < 2; i++) {
      const int row = i * 64 + wid * 16 + srow;
      const int col = kk + ((schunk ^ (row & 3)) << 3);
      __builtin_amdgcn_global_load_lds(AS1(A + (size_t)(m0 + row) * 1024 + col),
                                       AS3(&Als[bufi][(i * 64 + wid * 16) * 32]), 16, 0, 0);
      __builtin_amdgcn_global_load_lds(AS1(Bt + (size_t)(n0 + row) * 1024 + col),
                                       AS3(&Bls[bufi][(i * 64 + wid * 16) * 32]), 16, 0, 0);
    }
  };

  f32x4 acc[4][4] = {};
  STAGE(0, 0);
  STAGE(32, 1);
  for (int t = 0; t < 32; t++) {
    const int buf = t & 1;
    if (t < 31) {
      asm volatile("s_waitcnt vmcnt(4)" ::: "memory");
    } else {
      asm volatile("s_waitcnt vmcnt(0)" ::: "memory");
    }
    __builtin_amdgcn_sched_barrier(0);
    __builtin_amdgcn_s_barrier();
    __builtin_amdgcn_sched_barrier(0);
    s16x8 af[4], bfr[4];
#pragma unroll
    for (int mi = 0; mi < 4; mi++) {
      const int r = wm * 64 + mi * 16 + c;
      af[mi] = *(const s16x8*)&Als[buf][r * 32 + ((g ^ (r & 3)) << 3)];
    }
#pragma unroll
    for (int ni = 0; ni < 4; ni++) {
      const int r = wn * 64 + ni * 16 + c;
      bfr[ni] = *(const s16x8*)&Bls[buf][r * 32 + ((g ^ (r & 3)) << 3)];
    }
    asm volatile("s_waitcnt lgkmcnt(0)" ::: "memory");
    __builtin_amdgcn_sched_barrier(0);
    __builtin_amdgcn_s_barrier();
    __builtin_amdgcn_sched_barrier(0);
    if (t < 30) STAGE((t + 2) * 32, buf);
    __builtin_amdgcn_s_setprio(1);
#pragma unroll
    for (int mi = 0; mi < 4; mi++)
#pragma unroll
      for (int ni = 0; ni < 4; ni++)
        acc[mi][ni] = __builtin_amdgcn_mfma_f32_16x16x32_bf16(af[mi], bfr[ni],
                                                              acc[mi][ni], 0, 0, 0);
    __builtin_amdgcn_s_setprio(0);
  }
#pragma unroll
  for (int mi = 0; mi < 4; mi++) {
#pragma unroll
    for (int ni = 0; ni < 4; ni++) {
      const int gn = n0 + wn * 64 + ni * 16 + c;
      const float bb = bias[gn];
      const int gmb = m0 + wm * 64 + mi * 16 + (g << 2);
      const int hd = gn >> 6, d = gn & 63;
      if (mode == 2) {
        const int b = gmb >> 11, s0 = gmb & 2047;
        const int tile = s0 >> 6;
        const int jb = gmb & 63;
        const int j5b = jb & 31;
        const int posb = ((jb >> 5) << 5) + (((j5b & 15) >> 2) << 3) + ((j5b >> 4) << 2);
        s16x4 st;
#pragma unroll
        for (int r = 0; r < 4; r++) st[r] = (short)f2bf(acc[mi][ni][r] + bb);
        *(s16x4*)&Vt[(((size_t)b * 16 + hd) * 64 + d) * 2048 + tile * 64 + posb] = st;
      } else {
#pragma unroll
        for (int r = 0; r < 4; r++) {
          const int gm = gmb + r;
          float val = acc[mi][ni][r] + bb;
          const int b = gm >> 11, s = gm & 2047;
          if (mode == 0) val *= 0.18033688f;  // 0.125 * log2(e)
          outp[(((size_t)b * 16 + hd) * 2048 + s) * 64 + d] = f2bf(val);
        }
      }
    }
  }
}

// ---------------- output GEMM: 128x64, BK=32 dbuf counted-vmcnt, XCD-swizzled ----------------
__global__ __launch_bounds__(256) void gemm_out(const u16* __restrict__ A,
                                                const u16* __restrict__ Bt,
                                                const float* __restrict__ bias,
                                                float* __restrict__ outp) {
  __shared__ u16 Als[2][128 * 32];
  __shared__ u16 Bls[2][64 * 32];
  const int tid = threadIdx.x;
  const int lane = tid & 63;
  const int wid = tid >> 6;
  const int sid = blockIdx.x + (blockIdx.y << 4);
  const int xcd = sid & 7, sj = sid >> 3;
  const int m0 = ((xcd << 2) + (sj & 3)) * 128;
  const int n0 = (sj >> 2) * 64;
  const int g = lane >> 4, c = lane & 15;
  const int srow = lane >> 2, schunk = lane & 3;

  auto STAGE = [&](int kk, int bufi) {
#pragma unroll
    for (int i = 0; i < 2; i++) {
      const int row = i * 64 + wid * 16 + srow;
      const int col = kk + ((schunk ^ (row & 3)) << 3);
      __builtin_amdgcn_global_load_lds(AS1(A + (size_t)(m0 + row) * 1024 + col),
                                       AS3(&Als[bufi][(i * 64 + wid * 16) * 32]), 16, 0, 0);
    }
    {
      const int row = wid * 16 + srow;
      const int col = kk + ((schunk ^ (row & 3)) << 3);
      __builtin_amdgcn_global_load_lds(AS1(Bt + (size_t)(n0 + row) * 1024 + col),
                                       AS3(&Bls[bufi][(wid * 16) * 32]), 16, 0, 0);
    }
  };

  f32x4 acc[2][4] = {};
  STAGE(0, 0);
  STAGE(32, 1);
  for (int t = 0; t < 32; t++) {
    const int buf = t & 1;
    if (t < 31) {
      asm volatile("s_waitcnt vmcnt(3)" ::: "memory");
    } else {
      asm volatile("s_waitcnt vmcnt(0)" ::: "memory");
    }
    __builtin_amdgcn_sched_barrier(0);
    __builtin_amdgcn_s_barrier();
    __builtin_amdgcn_sched_barrier(0);
    s16x8 af[2], bfr[4];
#pragma unroll
    for (int mi = 0; mi < 2; mi++) {
      const int r = wid * 32 + mi * 16 + c;
      af[mi] = *(const s16x8*)&Als[buf][r * 32 + ((g ^ (r & 3)) << 3)];
    }
#pragma unroll
    for (int ni = 0; ni < 4; ni++) {
      const int r = ni * 16 + c;
      bfr[ni] = *(const s16x8*)&Bls[buf][r * 32 + ((g ^ (r & 3)) << 3)];
    }
    asm volatile("s_waitcnt lgkmcnt(0)" ::: "memory");
    __builtin_amdgcn_sched_barrier(0);
    __builtin_amdgcn_s_barrier();
    __builtin_amdgcn_sched_barrier(0);
    if (t < 30) STAGE((t + 2) * 32, buf);
    __builtin_amdgcn_s_setprio(1);
#pragma unroll
    for (int mi = 0; mi < 2; mi++)
#pragma unroll
      for (int ni = 0; ni < 4; ni++)
        acc[mi][ni] = __builtin_amdgcn_mfma_f32_16x16x32_bf16(af[mi], bfr[ni],
                                                              acc[mi][ni], 0, 0, 0);
    __builtin_amdgcn_s_setprio(0);
  }
#pragma unroll
  for (int mi = 0; mi < 2; mi++) {
#pragma unroll
    for (int ni = 0; ni < 4; ni++) {
      const int gn = n0 + ni * 16 + c;
      const float bb = bias[gn];
      const int gmb = m0 + wid * 32 + mi * 16 + (g << 2);
#pragma unroll
      for (int r = 0; r < 4; r++)
        outp[(size_t)(gmb + r) * 1024 + gn] = acc[mi][ni][r] + bb;
    }
  }
}

// ---------------- flash attention: MFMA ones-trick for l-sum ----------------
// l[q] = sum_kv P computed by lacc = mfma(ones16x32, pf, lacc) on the underutilized
// MFMA pipe (exact: A=const-ones is k-permutation-invariant). Removes 32 VALU adds/tile
// and the final cross-lane shuffles (every lane's lacc[qs][0] == l[its q-col c]).
__global__ __launch_bounds__(128) void attn_fwd(const u16* __restrict__ Qb,
                                                const u16* __restrict__ Kb,
                                                const u16* __restrict__ Vt,
                                                const float* __restrict__ mask,
                                                u16* __restrict__ ctx) {
  __shared__ u16 Kls[2][4096];
  __shared__ u16 Vls[2][4096];
  const int tid = threadIdx.x;
  const int lane = tid & 63, wid = tid >> 6;  // wid 0..1
  const int n = blockIdx.x;
  const int bh = ((n & 7) << 2) | ((n >> 3) & 3);  // 4 bh per XCD
  const int qblk = n >> 5;                          // 0..31
  const int b = bh >> 4, hd = bh & 15;
  const int g = lane >> 4, c = lane & 15;
  const int qbase = qblk * 64 + wid * 32;

  // reg-only all-zero mask detection (full-row scan per wave -> wave-uniform)
  const float* mp = mask + (size_t)b * 2048;
  int th_any = 0;
#pragma unroll
  for (int i = 0; i < 8; i++) {
    const f32x4 m4 = *(const f32x4*)(mp + lane * 32 + i * 4);
    th_any |= (m4[0] != 0.f) | (m4[1] != 0.f) | (m4[2] != 0.f) | (m4[3] != 0.f);
  }
  const int havemask = (__ballot(th_any) != 0ULL);

  // Q fragments for both 16-q subtiles, hoisted
  s16x8 qf[2][2];
#pragma unroll
  for (int sub = 0; sub < 2; sub++) {
    const u16* Qp = Qb + ((size_t)bh * 2048 + qbase + sub * 16 + c) * 64;
    qf[sub][0] = *(const s16x8*)(Qp + g * 8);
    qf[sub][1] = *(const s16x8*)(Qp + 32 + g * 8);
  }

  // all-ones bf16 A fragment for the l-sum MFMA
  s16x8 onesf;
#pragma unroll
  for (int i = 0; i < 8; i++) onesf[i] = (short)0x3F80;

  const u16* Kbh = Kb + (size_t)bh * 2048 * 64;
  const u16* Vbh = Vt + (size_t)bh * 64 * 2048;

  const int srl = lane >> 3;
  const int sch0 = lane & 7;
  auto STAGE = [&](int kv0, int bufi) {
#pragma unroll
    for (int jj = 0; jj < 4; jj++) {
      const int rl = wid * 32 + jj * 8 + srl;
      const int sch = sch0 ^ (rl & 7);
      __builtin_amdgcn_global_load_lds(AS1(Kbh + (size_t)(kv0 + rl) * 64 + sch * 8),
                                       AS3(&Kls[bufi][wid * 2048 + jj * 512]), 16, 0, 0);
      __builtin_amdgcn_global_load_lds(AS1(Vbh + (size_t)rl * 2048 + kv0 + sch * 8),
                                       AS3(&Vls[bufi][wid * 2048 + jj * 512]), 16, 0, 0);
    }
  };

  f32x4 o[2][4] = {};
  f32x4 lacc[2] = {};

  STAGE(0, 0);
  STAGE(64, 1);

  for (int t = 0; t < 32; t++) {
    const int kv0 = t * 64;
    const int buf = t & 1;
    if (t < 31) {
      asm volatile("s_waitcnt vmcnt(8)" ::: "memory");
    } else {
      asm volatile("s_waitcnt vmcnt(0)" ::: "memory");
    }
    __builtin_amdgcn_sched_barrier(0);
    __builtin_amdgcn_s_barrier();
    __builtin_amdgcn_sched_barrier(0);

    // ---- QK^T: K fragment read once, used by both q-subtiles ----
    f32x4 sacc[2][4] = {};
#pragma unroll
    for (int kvt = 0; kvt < 4; kvt++) {
      const int row = kvt * 16 + c;
      const int s7 = row & 7;
      const s16x8 kf0 = *(const s16x8*)&Kls[buf][row * 64 + ((g ^ s7) << 3)];
      const s16x8 kf1 = *(const s16x8*)&Kls[buf][row * 64 + (((4 + g) ^ s7) << 3)];
      sacc[0][kvt] = __builtin_amdgcn_mfma_f32_16x16x32_bf16(kf0, qf[0][0], sacc[0][kvt], 0, 0, 0);
      sacc[0][kvt] = __builtin_amdgcn_mfma_f32_16x16x32_bf16(kf1, qf[0][1], sacc[0][kvt], 0, 0, 0);
      sacc[1][kvt] = __builtin_amdgcn_mfma_f32_16x16x32_bf16(kf0, qf[1][0], sacc[1][kvt], 0, 0, 0);
      sacc[1][kvt] = __builtin_amdgcn_mfma_f32_16x16x32_bf16(kf1, qf[1][1], sacc[1][kvt], 0, 0, 0);
    }

    // ---- V fragments -> regs (shared by both q-subtiles) ----
    s16x8 vreg[4][2];
#pragma unroll
    for (int dblk = 0; dblk < 4; dblk++) {
      const int row = dblk * 16 + c;
      const int s7 = row & 7;
      const u16* base = &Vls[buf][row * 64];
      vreg[dblk][0] = *(const s16x8*)(base + ((g ^ s7) << 3));
      vreg[dblk][1] = *(const s16x8*)(base + (((4 + g) ^ s7) << 3));
    }
    // ---- release: all reads of buf done across block -> safe to restage ----
    asm volatile("s_waitcnt lgkmcnt(0)" ::: "memory");
    __builtin_amdgcn_sched_barrier(0);
    __builtin_amdgcn_s_barrier();
    __builtin_amdgcn_sched_barrier(0);
    if (t < 30) STAGE(kv0 + 128, buf);

    // ---- softmax: exp2 + pack (l-sum moved to MFMA) ----
    s16x8 pf[2][2];
    if (!havemask) {
#pragma unroll
      for (int qs = 0; qs < 2; qs++) {
        f32x4 p4[4];
#pragma unroll
        for (int kvt = 0; kvt < 4; kvt++)
#pragma unroll
          for (int jj = 0; jj < 4; jj++)
            p4[kvt][jj] = __builtin_amdgcn_exp2f(sacc[qs][kvt][jj]);
#pragma unroll
        for (int sub = 0; sub < 2; sub++) {
          u32x4 ww;
          ww[0] = cvtpk(p4[sub * 2][0], p4[sub * 2][1]);
          ww[1] = cvtpk(p4[sub * 2][2], p4[sub * 2][3]);
          ww[2] = cvtpk(p4[sub * 2 + 1][0], p4[sub * 2 + 1][1]);
          ww[3] = cvtpk(p4[sub * 2 + 1][2], p4[sub * 2 + 1][3]);
          pf[qs][sub] = __builtin_bit_cast(s16x8, ww);
        }
      }
    } else {
      f32x4 mk[4];
#pragma unroll
      for (int kvt = 0; kvt < 4; kvt++)
        mk[kvt] = *(const f32x4*)(mp + kv0 + kvt * 16 + 4 * g);
#pragma unroll
      for (int qs = 0; qs < 2; qs++) {
        f32x4 p4[4];
#pragma unroll
        for (int kvt = 0; kvt < 4; kvt++)
#pragma unroll
          for (int jj = 0; jj < 4; jj++)
            p4[kvt][jj] = __builtin_amdgcn_exp2f(fmaf(mk[kvt][jj], -1.44269504e9f,
                                                      sacc[qs][kvt][jj]));
#pragma unroll
        for (int sub = 0; sub < 2; sub++) {
          u32x4 ww;
          ww[0] = cvtpk(p4[sub * 2][0], p4[sub * 2][1]);
          ww[1] = cvtpk(p4[sub * 2][2], p4[sub * 2][3]);
          ww[2] = cvtpk(p4[sub * 2 + 1][0], p4[sub * 2 + 1][1]);
          ww[3] = cvtpk(p4[sub * 2 + 1][2], p4[sub * 2 + 1][3]);
          pf[qs][sub] = __builtin_bit_cast(s16x8, ww);
        }
      }
    }
    // NOTE: bf16 rounding of P happens before BOTH the l-sum and PV -> consistent
    // normalization (matches prior rounds' arithmetic to bf16 precision).

    // ---- l-sum via ones-MFMA + PV from registers ----
#pragma unroll
    for (int subk = 0; subk < 2; subk++) {
      lacc[0] = __builtin_amdgcn_mfma_f32_16x16x32_bf16(onesf, pf[0][subk], lacc[0], 0, 0, 0);
      lacc[1] = __builtin_amdgcn_mfma_f32_16x16x32_bf16(onesf, pf[1][subk], lacc[1], 0, 0, 0);
    }
#pragma unroll
    for (int dblk = 0; dblk < 4; dblk++)
#pragma unroll
      for (int subk = 0; subk < 2; subk++) {
        o[0][dblk] = __builtin_amdgcn_mfma_f32_16x16x32_bf16(vreg[dblk][subk], pf[0][subk], o[0][dblk], 0, 0, 0);
        o[1][dblk] = __builtin_amdgcn_mfma_f32_16x16x32_bf16(vreg[dblk][subk], pf[1][subk], o[1][dblk], 0, 0, 0);
      }
  }

#pragma unroll
  for (int qs = 0; qs < 2; qs++) {
    const float inv = 1.0f / lacc[qs][0];  // every lane: l for its own q-col c
    u16* cp = ctx + ((size_t)b * 2048 + qbase + qs * 16 + c) * 1024 + hd * 64;
#pragma unroll
    for (int d = 0; d < 4; d++) {
      u32x2 st;
      st[0] = cvtpk(o[qs][d][0] * inv, o[qs][d][1] * inv);
      st[1] = cvtpk(o[qs][d][2] * inv, o[qs][d][3] * inv);
      *(u32x2*)&cp[d * 16 + 4 * g] = st;
    }
  }
}

extern "C" void kernel_launch(void* const* d_in, const int* in_sizes, int n_in,
                              void* d_out, int out_size, void* d_ws, size_t ws_size,
                              hipStream_t stream) {
  (void)in_sizes; (void)n_in; (void)out_size; (void)ws_size;
  const float* q = (const float*)d_in[0];
  const float* k = (const float*)d_in[1];
  const float* v = (const float*)d_in[2];
  const float* mask = (const float*)d_in[3];
  const float* wq = (const float*)d_in[4];
  const float* bq = (const float*)d_in[5];
  const float* wk = (const float*)d_in[6];
  const float* bk = (const float*)d_in[7];
  const float* wv = (const float*)d_in[8];
  const float* bv = (const float*)d_in[9];
  const float* wo = (const float*)d_in[10];
  const float* bo = (const float*)d_in[11];
  float* out = (float*)d_out;
  char* ws = (char*)d_ws;
  const size_t MB = (size_t)1 << 20;
  u16* Xq = (u16*)(ws + 0 * MB);
  u16* Xk = (u16*)(ws + 8 * MB);
  u16* Xv = (u16*)(ws + 16 * MB);
  u16* Wqt = (u16*)(ws + 24 * MB);
  u16* Wkt = (u16*)(ws + 26 * MB);
  u16* Wvt = (u16*)(ws + 28 * MB);
  u16* Wot = (u16*)(ws + 30 * MB);
  u16* Qb = (u16*)(ws + 32 * MB);
  u16* Kb = (u16*)(ws + 40 * MB);
  u16* Vt = (u16*)(ws + 48 * MB);
  u16* ctx = Xq;  // alias: Xq dead once attn runs

  prep<<<10240, 256, 0, stream>>>(q, k, v, wq, wk, wv, wo, Xq, Xk, Xv, Wqt, Wkt, Wvt, Wot);
  gemm_qkv<<<dim3(8, 32, 3), 256, 0, stream>>>(Xq, Xk, Xv, Wqt, Wkt, Wvt, bq, bk, bv,
                                               Qb, Kb, Vt);
  attn_fwd<<<1024, 128, 0, stream>>>(Qb, Kb, Vt, mask, ctx);
  gemm_out<<<dim3(16, 32), 256, 0, stream>>>(ctx, Wot, bo, out);
}